// Round 9
// baseline (437.085 us; speedup 1.0000x reference)
//
#include <hip/hip_runtime.h>
#include <math.h>

namespace {

constexpr int Bn = 16, Tn = 512, Dn = 768, Sn = 4, Hn = 48, On = 48;
constexpr int Mn = Bn * Tn;          // 8192 (b,t) rows
constexpr int Gn = Sn * Hn;          // 192 (s,h) groups
constexpr int Nn = Gn * On;          // 9216 flat N (= flat W rows)
constexpr float EMISS_W = 0.5f;

// workspace layout (float offsets), then bf16 regions ~27 MB
constexpr size_t OFF_LP   = 0;
constexpr size_t OFF_LT   = 64;
constexpr size_t OFF_PT   = OFF_LT + Hn*Hn;
constexpr size_t OFF_EM   = OFF_PT + Hn*Hn;
constexpr size_t OFF_LEPP = OFF_EM + (size_t)Sn*Hn*On;   // [m][g] g = s*48+h (log partials)
constexpr size_t OFF_LA   = OFF_LEPP + (size_t)Mn*Gn;    // alpha probs (per-t scale)
constexpr size_t OFF_LB   = OFF_LA + (size_t)Mn*Hn;      // beta probs (per-t scale)
constexpr size_t OFF_RED  = OFF_LB + (size_t)Mn*Hn;      // per-(b,t) partials [8192]
constexpr size_t OFF_CNT  = OFF_RED + (size_t)Mn;        // completion counter (int)
constexpr size_t FLOATS_END = OFF_CNT + 64;

typedef __attribute__((ext_vector_type(8))) short short8;
typedef __attribute__((ext_vector_type(4))) float f32x4;

__device__ inline float waveSum(float v){
#pragma unroll
  for (int o = 32; o; o >>= 1) v += __shfl_xor(v, o);
  return v;
}

__device__ inline unsigned short f2bf(float f){
  unsigned int u = __float_as_uint(f);
  u += 0x7FFFu + ((u >> 16) & 1u);   // round-to-nearest-even
  return (unsigned short)(u >> 16);
}

__device__ inline void gload_lds16(const void* g, void* l){
  __builtin_amdgcn_global_load_lds(
      (const __attribute__((address_space(1))) void*)g,
      (__attribute__((address_space(3))) void*)l, 16, 0, 0);
}

// -------- conversion (all blocks but last) + param preprocessing (last block) --
__global__ void convprep_kernel(const float* __restrict__ srcA, unsigned short* __restrict__ dstA,
                                int n4a,
                                const float* __restrict__ srcB, unsigned short* __restrict__ dstB,
                                int n4b,
                                const float* __restrict__ sp, const float* __restrict__ ut,
                                const float* __restrict__ ue, float* __restrict__ ws,
                                int nconv){
  const int tid = threadIdx.x;
  if ((int)blockIdx.x == nconv){
    // ---- prep ----
    if (tid == 0) ((unsigned int*)(ws + OFF_CNT))[0] = 0u;   // last-block counter
    float m = -INFINITY;
    for (int h = 0; h < Hn; ++h) m = fmaxf(m, sp[h]);
    float s = 0.f;
    for (int h = 0; h < Hn; ++h) s += __expf(sp[h] - m);
    float lse = m + __logf(s);
    if (tid < Hn) ws[OFF_LP + tid] = sp[tid] - lse;
    if (tid < Hn){
      const float* row = ut + tid * Hn;
      float mm = -INFINITY;
      for (int j = 0; j < Hn; ++j) mm = fmaxf(mm, row[j]);
      float ss = 0.f;
      for (int j = 0; j < Hn; ++j) ss += __expf(row[j] - mm);
      float l = mm + __logf(ss);
      for (int j = 0; j < Hn; ++j){
        float v = row[j] - l;
        ws[OFF_LT + tid*Hn + j] = v;
        ws[OFF_PT + tid*Hn + j] = __expf(v);
      }
    }
    for (int r = tid; r < Sn*Hn; r += blockDim.x){
      const float* row = ue + (size_t)r * On;
      float mm = -INFINITY;
      for (int o = 0; o < On; ++o) mm = fmaxf(mm, row[o]);
      float ss = 0.f;
      for (int o = 0; o < On; ++o) ss += __expf(row[o] - mm);
      float inv = 1.f/ss;
      for (int o = 0; o < On; ++o) ws[OFF_EM + (size_t)r*On + o] = __expf(row[o]-mm)*inv;
    }
    return;
  }
  // ---- conv ----
  int i = blockIdx.x * blockDim.x + tid;
  const float* s2; unsigned short* d; int k;
  if (i < n4a){ s2 = srcA; d = dstA; k = i; }
  else { k = i - n4a; if (k >= n4b) return; s2 = srcB; d = dstB; }
  float4 v = ((const float4*)s2)[k];
  ushort4 r;
  r.x = f2bf(v.x); r.y = f2bf(v.y); r.z = f2bf(v.z); r.w = f2bf(v.w);
  ((ushort4*)d)[k] = r;
}

// ---------------- bf16 MFMA GEMM + fused softmax/mix/obs-dot epilogue ----------
// R7 config (best measured: 147.5us, VGPR 84): 128x96 tile, KT=64, C-park in
// LDS, hw-exp epilogue without max pass (logits ~N(0,1), no overflow risk).
constexpr int MT = 128, NT2 = 96, KT = 64;

__global__ __launch_bounds__(256) void gemm_lep_kernel(
    const unsigned short* __restrict__ embB, const unsigned short* __restrict__ WB,
    const float* __restrict__ bm, const float* __restrict__ obs,
    float* __restrict__ ws){
  __shared__ __align__(16) char smem[128*97*4];   // 49664 B (staging aliased by C)
  __shared__ float bias_s[96], em_s[96];
  const int tid = threadIdx.x, lane = tid & 63, w = tid >> 6;
  const int m0 = blockIdx.x * MT;
  const int N0 = blockIdx.y * NT2;
  if (tid < 96){
    bias_s[tid] = bm[N0 + tid];
    em_s[tid]   = ws[OFF_EM + N0 + tid];
  }
  const int wm = w & 1, wn = w >> 1;
  const int lm = lane & 15, q = lane >> 4;
  const int key = lm & 7;
  const int srow = lane >> 3, spc = lane & 7;

  f32x4 acc[4][3];
#pragma unroll
  for (int i=0;i<4;++i)
#pragma unroll
    for (int j=0;j<3;++j) acc[i][j] = (f32x4){0.f,0.f,0.f,0.f};

  for (int kc = 0; kc < Dn; kc += KT){
    __syncthreads();
#pragma unroll
    for (int i=0;i<4;++i){
      int idx = w*4 + i;
      int row = idx*8 + srow;
      int lc  = spc ^ (row & 7);
      gload_lds16(embB + (size_t)(m0+row)*Dn + kc + lc*8, smem + idx*1024);
    }
#pragma unroll
    for (int i=0;i<3;++i){
      int idx = w*3 + i;
      int row = idx*8 + srow;
      int lc  = spc ^ (row & 7);
      gload_lds16(WB + (size_t)(N0+row)*Dn + kc + lc*8, smem + 16384 + idx*1024);
    }
    __syncthreads();
#pragma unroll
    for (int s = 0; s < 2; ++s){
      short8 af[4], bf[3];
#pragma unroll
      for (int i=0;i<4;++i){
        int row = wm*64 + i*16 + lm;
        af[i] = *(const short8*)(smem + row*128 + (((s*4+q) ^ key) * 16));
      }
#pragma unroll
      for (int j=0;j<3;++j){
        int row = wn*48 + j*16 + lm;
        bf[j] = *(const short8*)(smem + 16384 + row*128 + (((s*4+q) ^ key) * 16));
      }
#pragma unroll
      for (int i=0;i<4;++i)
#pragma unroll
        for (int j=0;j<3;++j)
          acc[i][j] = __builtin_amdgcn_mfma_f32_16x16x32_bf16(af[i], bf[j], acc[i][j], 0, 0, 0);
    }
  }
  __syncthreads();
  // park C (f32, stride 97) over the staging region
  float* C = (float*)smem;
#pragma unroll
  for (int i=0;i<4;++i)
#pragma unroll
    for (int j=0;j<3;++j)
#pragma unroll
      for (int r=0;r<4;++r){
        int mrow = wm*64 + i*16 + q*4 + r;
        int ncol = wn*48 + j*16 + lm;
        C[mrow*97 + ncol] = acc[i][j][r];
      }
  __syncthreads();
  // epilogue: thread -> (row, group-half); hw-exp softmax, mix, obs-dot, log
  {
    const int row = tid >> 1, half = tid & 1;
    const int m = m0 + row;
    const int g = N0/48 + half;
    const int s2 = g / Hn;
    const float* crow = C + row*97 + half*48;
    const float* ob   = obs + ((size_t)m*Sn + s2)*On;
    const float* bi   = bias_s + half*48;
    const float* em   = em_s + half*48;
    float Z=0.f, pd=0.f, eo=0.f;
#pragma unroll
    for (int o=0;o<On;++o){
      float e = __expf(crow[o] + bi[o]);
      float obv = ob[o];
      Z += e;
      pd = fmaf(e, obv, pd);
      eo = fmaf(em[o], obv, eo);
    }
    float val = __logf((1.f-EMISS_W)*eo + EMISS_W*(pd/Z));
    ws[OFF_LEPP + (size_t)m*Gn + g] = val;
  }
}

// ---------------- forward/backward recursions: chunked with warm-up ----------
// Serial depth 40 (FBW warm-up + FBL chunk). Stages exp(sum of 4 lep
// partials) straight from OFF_LEPP (lep_reduce kernel deleted).
constexpr int FBW = 24;   // warm-up steps
constexpr int FBL = 16;   // chunk length

__global__ __launch_bounds__(64) void fb_kernel(float* __restrict__ ws){
  __shared__ __align__(16) float ldsE[(FBW+FBL)*48];   // exp(lep) window
  __shared__ __align__(16) float ring[2][64];
  const int lane = threadIdx.x;
  const int c    = blockIdx.x;
  const int b    = blockIdx.y;
  const bool fwd = blockIdx.z == 0;
  const bool act = lane < Hn;
  const int t0 = c*FBL, te = t0 + FBL - 1;

  float pt[Hn];
#pragma unroll
  for (int i = 0; i < Hn; ++i)
    pt[i] = act ? (fwd ? ws[OFF_PT + i*Hn + lane] : ws[OFF_PT + lane*Hn + i]) : 0.f;

  int row_lo, nrows, sA, sZ;
  bool exact;
  if (fwd){
    sA = t0 - FBW;
    exact = (sA < 1);
    row_lo = exact ? 0 : sA;
    if (exact) sA = 1;
    sZ = te;
    nrows = te - row_lo + 1;
  } else {
    int th = te + 1 + FBW;
    exact = (th > Tn - 2);
    sA = exact ? Tn - 2 : th - 1;
    sZ = t0;
    row_lo = t0;
    nrows = sA - t0 + 1;
  }

  // stage exp(lep) = exp(sum of 4 partials) from [m][192] layout
  {
    const float* src = ws + OFF_LEPP + ((size_t)b*Tn + row_lo)*Gn;
    int n4 = nrows * (Hn/4);
    for (int i = lane; i < n4; i += 64){
      int r = i / (Hn/4), h4 = i - r*(Hn/4);
      const float* p = src + (size_t)r*Gn + h4*4;
      float4 a = *(const float4*)(p);
      float4 b2 = *(const float4*)(p + Hn);
      float4 c2 = *(const float4*)(p + 2*Hn);
      float4 d2 = *(const float4*)(p + 3*Hn);
      float4 e;
      e.x = __expf(a.x + b2.x + c2.x + d2.x);
      e.y = __expf(a.y + b2.y + c2.y + d2.y);
      e.z = __expf(a.z + b2.z + c2.z + d2.z);
      e.w = __expf(a.w + b2.w + c2.w + d2.w);
      ((float4*)ldsE)[i] = e;
    }
  }
  __syncthreads();

  if (fwd){
    const size_t laF = OFF_LA + (size_t)b * Tn * Hn;
    float v;
    if (exact){
      v = act ? __expf(ws[OFF_LP + lane]) * ldsE[lane] : 0.f;   // alpha_0
      if (c == 0 && act) ws[laF + lane] = v;
    } else {
      v = act ? 1.f : 0.f;
    }
    if (act) ring[0][lane] = v;
    __syncthreads();
    int cur = 0;
    for (int t = sA; t <= sZ; ++t){
      float S = waveSum(v);
      const float* rp = ring[cur];
      float s0=0.f,s1=0.f,s2=0.f,s3=0.f;
#pragma unroll
      for (int i = 0; i < Hn; i += 4){
        float4 a = *(const float4*)(rp + i);
        s0 = fmaf(a.x, pt[i+0], s0); s1 = fmaf(a.y, pt[i+1], s1);
        s2 = fmaf(a.z, pt[i+2], s2); s3 = fmaf(a.w, pt[i+3], s3);
      }
      float sd = (s0+s1)+(s2+s3);
      float e = act ? ldsE[(t - row_lo)*Hn + lane] : 0.f;
      float vn = act ? e * sd * (1.f/S) : 0.f;
      cur ^= 1;
      if (act) ring[cur][lane] = vn;
      __syncthreads();
      if (act && t >= t0) ws[laF + (size_t)t*Hn + lane] = vn;
      v = vn;
    }
  } else {
    const size_t lbF = OFF_LB + (size_t)b * Tn * Hn;
    float v = act ? 1.f : 0.f;
    if (exact && c == (Tn/FBL - 1) && act) ws[lbF + (size_t)(Tn-1)*Hn + lane] = 1.f;
    int cur = 0;
    for (int t = sA; t >= sZ; --t){
      float e = act ? ldsE[(t - row_lo)*Hn + lane] : 0.f;
      float wv = e * v;
      if (act) ring[cur][lane] = wv;
      float S = waveSum(wv);
      __syncthreads();
      const float* rp = ring[cur];
      float s0=0.f,s1=0.f,s2=0.f,s3=0.f;
#pragma unroll
      for (int j = 0; j < Hn; j += 4){
        float4 a = *(const float4*)(rp + j);
        s0 = fmaf(a.x, pt[j+0], s0); s1 = fmaf(a.y, pt[j+1], s1);
        s2 = fmaf(a.z, pt[j+2], s2); s3 = fmaf(a.w, pt[j+3], s3);
      }
      float vn = act ? ((s0+s1)+(s2+s3)) * (1.f/S) : 0.f;
      cur ^= 1;
      if (act && t <= te) ws[lbF + (size_t)t*Hn + lane] = vn;
      v = vn;
    }
  }
}

// -------- gamma / xi / masked accumulation + last-block final reduction --------
__global__ __launch_bounds__(256) void gamma_xi_kernel(
    const float* __restrict__ ws_c, float* __restrict__ ws,
    const int* __restrict__ seq_len, float* __restrict__ out){
  __shared__ float y_s[Hn], lap_s[Hn];
  __shared__ float red[8];
  __shared__ int isLast;
  const int tid = threadIdx.x;
  const int bid = blockIdx.x;
  const int b = bid >> 9, t = bid & (Tn-1);
  const int len = seq_len[b];
  int tb = t + (Tn - len); if (tb >= Tn) tb -= Tn;
  const size_t bt = (size_t)b*Tn + t;
  float lep = 0.f;
  if (tid < Hn){
    const float* lpp = ws_c + OFF_LEPP + bt*Gn + tid;
    lep = lpp[0] + lpp[Hn] + lpp[2*Hn] + lpp[3*Hn];
    float lb  = ws_c[OFF_LB + ((size_t)b*Tn + tb)*Hn + tid];
    y_s[tid] = __expf(lep) * lb;
    if (t >= 1) lap_s[tid] = ws_c[OFF_LA + (bt-1)*Hn + tid];
  }
  float emis_term = 0.f, prior_term = 0.f;
  if (tid < 64){
    int h = (tid < Hn) ? tid : 0;
    float la  = ws_c[OFF_LA + bt*Hn + h];
    float lb  = ws_c[OFF_LB + ((size_t)b*Tn + tb)*Hn + h];
    float lp  = ws_c[OFF_LP + h];
    float wgt = (tid < Hn) ? la*lb : 0.f;
    float Z = waveSum(wgt);
    float inv = 1.f / Z;
    emis_term  = waveSum(wgt * lep) * inv;
    prior_term = waveSum(wgt * lp) * inv;
  }
  __syncthreads();
  float tran_term = 0.f;
  if (t >= 1){
    float se = 0.f, st = 0.f;
#pragma unroll
    for (int k=0;k<9;++k){
      int e = tid + k*256;
      int i = e / Hn, j = e - i*Hn;
      float e2 = ws_c[OFF_PT + e] * lap_s[i] * y_s[j];
      se += e2;
      st = fmaf(e2, ws_c[OFF_LT + e], st);
    }
    se = waveSum(se);
    st = waveSum(st);
    const int wid = tid >> 6;
    if ((tid & 63) == 0){ red[wid] = se; red[4+wid] = st; }
    __syncthreads();
    if (tid == 0){
      float SE = red[0]+red[1]+red[2]+red[3];
      float ST = red[4]+red[5]+red[6]+red[7];
      tran_term = ST / SE;
    }
  }
  if (tid == 0){
    float tot = 0.f;
    if (t < len)            tot += emis_term;
    if (t == 0)             tot += prior_term;
    if (t >= 1 && t < len)  tot += tran_term;
    ws[OFF_RED + bid] = tot;
    __threadfence();
    unsigned old = atomicAdd((unsigned*)(ws + OFF_CNT), 1u);
    isLast = (old == (unsigned)(Mn - 1)) ? 1 : 0;
  }
  __syncthreads();
  if (isLast){
    __threadfence();
    float s = 0.f;
    for (int i = tid; i < Mn; i += 256) s += ws[OFF_RED + i];
    s = waveSum(s);
    if ((tid & 63) == 0) red[tid >> 6] = s;
    __syncthreads();
    if (tid == 0) out[0] = (red[0]+red[1]+red[2]+red[3]) * (1.f / Bn);
  }
}

} // namespace

extern "C" void kernel_launch(void* const* d_in, const int* in_sizes, int n_in,
                              void* d_out, int out_size, void* d_ws, size_t ws_size,
                              hipStream_t stream){
  const float* emb = (const float*)d_in[0];
  const float* obs = (const float*)d_in[1];
  const float* sp  = (const float*)d_in[2];
  const float* ut  = (const float*)d_in[3];
  const float* ue  = (const float*)d_in[4];
  const float* Wm  = (const float*)d_in[5];
  const float* bm  = (const float*)d_in[6];
  const int*   sl  = (const int*)d_in[7];
  float* ws  = (float*)d_ws;
  float* out = (float*)d_out;
  (void)in_sizes; (void)n_in; (void)ws_size; (void)out_size;

  unsigned short* embB = (unsigned short*)(ws + FLOATS_END);
  unsigned short* WB   = embB + (size_t)Mn * Dn;

  const int n4a = Mn*Dn/4, n4b = Nn*Dn/4;
  const int nconv = (n4a + n4b + 255)/256;
  convprep_kernel<<<nconv + 1, 256, 0, stream>>>(emb, embB, n4a, Wm, WB, n4b,
                                                 sp, ut, ue, ws, nconv);
  gemm_lep_kernel<<<dim3(Mn/MT, Nn/NT2), 256, 0, stream>>>(embB, WB, bm, obs, ws);
  fb_kernel<<<dim3(Tn/FBL, Bn, 2), 64, 0, stream>>>(ws);
  gamma_xi_kernel<<<Bn*Tn, 256, 0, stream>>>(ws, ws, sl, out);
}

// Round 10
// 295.120 us; speedup vs baseline: 1.4810x; 1.4810x over previous
//
#include <hip/hip_runtime.h>
#include <math.h>

namespace {

constexpr int Bn = 16, Tn = 512, Dn = 768, Sn = 4, Hn = 48, On = 48;
constexpr int Mn = Bn * Tn;          // 8192 (b,t) rows
constexpr int Gn = Sn * Hn;          // 192 (s,h) groups
constexpr int Nn = Gn * On;          // 9216 flat N (= flat W rows)
constexpr float EMISS_W = 0.5f;

// workspace layout (float offsets), then bf16 regions ~27 MB
constexpr size_t OFF_LP   = 0;
constexpr size_t OFF_LT   = 64;
constexpr size_t OFF_PT   = OFF_LT + Hn*Hn;
constexpr size_t OFF_EM   = OFF_PT + Hn*Hn;
constexpr size_t OFF_LEPP = OFF_EM + (size_t)Sn*Hn*On;   // [m][g] g = s*48+h (log partials)
constexpr size_t OFF_LA   = OFF_LEPP + (size_t)Mn*Gn;    // alpha probs (per-t scale)
constexpr size_t OFF_LB   = OFF_LA + (size_t)Mn*Hn;      // beta probs (per-t scale)
constexpr size_t OFF_RED  = OFF_LB + (size_t)Mn*Hn;      // per-(b,t) partials [8192]
constexpr size_t FLOATS_END = OFF_RED + (size_t)Mn;

typedef __attribute__((ext_vector_type(8))) short short8;
typedef __attribute__((ext_vector_type(4))) float f32x4;

__device__ inline float waveSum(float v){
#pragma unroll
  for (int o = 32; o; o >>= 1) v += __shfl_xor(v, o);
  return v;
}

__device__ inline unsigned short f2bf(float f){
  unsigned int u = __float_as_uint(f);
  u += 0x7FFFu + ((u >> 16) & 1u);   // round-to-nearest-even
  return (unsigned short)(u >> 16);
}

__device__ inline void gload_lds16(const void* g, void* l){
  __builtin_amdgcn_global_load_lds(
      (const __attribute__((address_space(1))) void*)g,
      (__attribute__((address_space(3))) void*)l, 16, 0, 0);
}

// -------- conversion (all blocks but last) + param preprocessing (last block) --
__global__ void convprep_kernel(const float* __restrict__ srcA, unsigned short* __restrict__ dstA,
                                int n4a,
                                const float* __restrict__ srcB, unsigned short* __restrict__ dstB,
                                int n4b,
                                const float* __restrict__ sp, const float* __restrict__ ut,
                                const float* __restrict__ ue, float* __restrict__ ws,
                                int nconv){
  const int tid = threadIdx.x;
  if ((int)blockIdx.x == nconv){
    // ---- prep ----
    float m = -INFINITY;
    for (int h = 0; h < Hn; ++h) m = fmaxf(m, sp[h]);
    float s = 0.f;
    for (int h = 0; h < Hn; ++h) s += __expf(sp[h] - m);
    float lse = m + __logf(s);
    if (tid < Hn) ws[OFF_LP + tid] = sp[tid] - lse;
    if (tid < Hn){
      const float* row = ut + tid * Hn;
      float mm = -INFINITY;
      for (int j = 0; j < Hn; ++j) mm = fmaxf(mm, row[j]);
      float ss = 0.f;
      for (int j = 0; j < Hn; ++j) ss += __expf(row[j] - mm);
      float l = mm + __logf(ss);
      for (int j = 0; j < Hn; ++j){
        float v = row[j] - l;
        ws[OFF_LT + tid*Hn + j] = v;
        ws[OFF_PT + tid*Hn + j] = __expf(v);
      }
    }
    for (int r = tid; r < Sn*Hn; r += blockDim.x){
      const float* row = ue + (size_t)r * On;
      float mm = -INFINITY;
      for (int o = 0; o < On; ++o) mm = fmaxf(mm, row[o]);
      float ss = 0.f;
      for (int o = 0; o < On; ++o) ss += __expf(row[o] - mm);
      float inv = 1.f/ss;
      for (int o = 0; o < On; ++o) ws[OFF_EM + (size_t)r*On + o] = __expf(row[o]-mm)*inv;
    }
    return;
  }
  // ---- conv ----
  int i = blockIdx.x * blockDim.x + tid;
  const float* s2; unsigned short* d; int k;
  if (i < n4a){ s2 = srcA; d = dstA; k = i; }
  else { k = i - n4a; if (k >= n4b) return; s2 = srcB; d = dstB; }
  float4 v = ((const float4*)s2)[k];
  ushort4 r;
  r.x = f2bf(v.x); r.y = f2bf(v.y); r.z = f2bf(v.z); r.w = f2bf(v.w);
  ((ushort4*)d)[k] = r;
}

// ---------------- bf16 MFMA GEMM + fused softmax/mix/obs-dot epilogue ----------
// R7 config (best measured: 147.5us, VGPR 84): 128x96 tile, KT=64, C-park in
// LDS, hw-exp epilogue without max pass (logits ~N(0,1), no overflow risk).
constexpr int MT = 128, NT2 = 96, KT = 64;

__global__ __launch_bounds__(256) void gemm_lep_kernel(
    const unsigned short* __restrict__ embB, const unsigned short* __restrict__ WB,
    const float* __restrict__ bm, const float* __restrict__ obs,
    float* __restrict__ ws){
  __shared__ __align__(16) char smem[128*97*4];   // 49664 B (staging aliased by C)
  __shared__ float bias_s[96], em_s[96];
  const int tid = threadIdx.x, lane = tid & 63, w = tid >> 6;
  const int m0 = blockIdx.x * MT;
  const int N0 = blockIdx.y * NT2;
  if (tid < 96){
    bias_s[tid] = bm[N0 + tid];
    em_s[tid]   = ws[OFF_EM + N0 + tid];
  }
  const int wm = w & 1, wn = w >> 1;
  const int lm = lane & 15, q = lane >> 4;
  const int key = lm & 7;
  const int srow = lane >> 3, spc = lane & 7;

  f32x4 acc[4][3];
#pragma unroll
  for (int i=0;i<4;++i)
#pragma unroll
    for (int j=0;j<3;++j) acc[i][j] = (f32x4){0.f,0.f,0.f,0.f};

  for (int kc = 0; kc < Dn; kc += KT){
    __syncthreads();
#pragma unroll
    for (int i=0;i<4;++i){
      int idx = w*4 + i;
      int row = idx*8 + srow;
      int lc  = spc ^ (row & 7);
      gload_lds16(embB + (size_t)(m0+row)*Dn + kc + lc*8, smem + idx*1024);
    }
#pragma unroll
    for (int i=0;i<3;++i){
      int idx = w*3 + i;
      int row = idx*8 + srow;
      int lc  = spc ^ (row & 7);
      gload_lds16(WB + (size_t)(N0+row)*Dn + kc + lc*8, smem + 16384 + idx*1024);
    }
    __syncthreads();
#pragma unroll
    for (int s = 0; s < 2; ++s){
      short8 af[4], bf[3];
#pragma unroll
      for (int i=0;i<4;++i){
        int row = wm*64 + i*16 + lm;
        af[i] = *(const short8*)(smem + row*128 + (((s*4+q) ^ key) * 16));
      }
#pragma unroll
      for (int j=0;j<3;++j){
        int row = wn*48 + j*16 + lm;
        bf[j] = *(const short8*)(smem + 16384 + row*128 + (((s*4+q) ^ key) * 16));
      }
#pragma unroll
      for (int i=0;i<4;++i)
#pragma unroll
        for (int j=0;j<3;++j)
          acc[i][j] = __builtin_amdgcn_mfma_f32_16x16x32_bf16(af[i], bf[j], acc[i][j], 0, 0, 0);
    }
  }
  __syncthreads();
  // park C (f32, stride 97) over the staging region
  float* C = (float*)smem;
#pragma unroll
  for (int i=0;i<4;++i)
#pragma unroll
    for (int j=0;j<3;++j)
#pragma unroll
      for (int r=0;r<4;++r){
        int mrow = wm*64 + i*16 + q*4 + r;
        int ncol = wn*48 + j*16 + lm;
        C[mrow*97 + ncol] = acc[i][j][r];
      }
  __syncthreads();
  // epilogue: thread -> (row, group-half); hw-exp softmax, mix, obs-dot, log
  {
    const int row = tid >> 1, half = tid & 1;
    const int m = m0 + row;
    const int g = N0/48 + half;
    const int s2 = g / Hn;
    const float* crow = C + row*97 + half*48;
    const float* ob   = obs + ((size_t)m*Sn + s2)*On;
    const float* bi   = bias_s + half*48;
    const float* em   = em_s + half*48;
    float Z=0.f, pd=0.f, eo=0.f;
#pragma unroll
    for (int o=0;o<On;++o){
      float e = __expf(crow[o] + bi[o]);
      float obv = ob[o];
      Z += e;
      pd = fmaf(e, obv, pd);
      eo = fmaf(em[o], obv, eo);
    }
    float val = __logf((1.f-EMISS_W)*eo + EMISS_W*(pd/Z));
    ws[OFF_LEPP + (size_t)m*Gn + g] = val;
  }
}

// ---------------- forward/backward recursions: chunked with warm-up ----------
// Serial depth 40 (FBW warm-up + FBL chunk). Stages exp(sum of 4 lep
// partials) straight from OFF_LEPP (lep_reduce kernel deleted).
constexpr int FBW = 24;   // warm-up steps
constexpr int FBL = 16;   // chunk length

__global__ __launch_bounds__(64) void fb_kernel(float* __restrict__ ws){
  __shared__ __align__(16) float ldsE[(FBW+FBL)*48];   // exp(lep) window
  __shared__ __align__(16) float ring[2][64];
  const int lane = threadIdx.x;
  const int c    = blockIdx.x;
  const int b    = blockIdx.y;
  const bool fwd = blockIdx.z == 0;
  const bool act = lane < Hn;
  const int t0 = c*FBL, te = t0 + FBL - 1;

  float pt[Hn];
#pragma unroll
  for (int i = 0; i < Hn; ++i)
    pt[i] = act ? (fwd ? ws[OFF_PT + i*Hn + lane] : ws[OFF_PT + lane*Hn + i]) : 0.f;

  int row_lo, nrows, sA, sZ;
  bool exact;
  if (fwd){
    sA = t0 - FBW;
    exact = (sA < 1);
    row_lo = exact ? 0 : sA;
    if (exact) sA = 1;
    sZ = te;
    nrows = te - row_lo + 1;
  } else {
    int th = te + 1 + FBW;
    exact = (th > Tn - 2);
    sA = exact ? Tn - 2 : th - 1;
    sZ = t0;
    row_lo = t0;
    nrows = sA - t0 + 1;
  }

  // stage exp(lep) = exp(sum of 4 partials) from [m][192] layout
  {
    const float* src = ws + OFF_LEPP + ((size_t)b*Tn + row_lo)*Gn;
    int n4 = nrows * (Hn/4);
    for (int i = lane; i < n4; i += 64){
      int r = i / (Hn/4), h4 = i - r*(Hn/4);
      const float* p = src + (size_t)r*Gn + h4*4;
      float4 a = *(const float4*)(p);
      float4 b2 = *(const float4*)(p + Hn);
      float4 c2 = *(const float4*)(p + 2*Hn);
      float4 d2 = *(const float4*)(p + 3*Hn);
      float4 e;
      e.x = __expf(a.x + b2.x + c2.x + d2.x);
      e.y = __expf(a.y + b2.y + c2.y + d2.y);
      e.z = __expf(a.z + b2.z + c2.z + d2.z);
      e.w = __expf(a.w + b2.w + c2.w + d2.w);
      ((float4*)ldsE)[i] = e;
    }
  }
  __syncthreads();

  if (fwd){
    const size_t laF = OFF_LA + (size_t)b * Tn * Hn;
    float v;
    if (exact){
      v = act ? __expf(ws[OFF_LP + lane]) * ldsE[lane] : 0.f;   // alpha_0
      if (c == 0 && act) ws[laF + lane] = v;
    } else {
      v = act ? 1.f : 0.f;
    }
    if (act) ring[0][lane] = v;
    __syncthreads();
    int cur = 0;
    for (int t = sA; t <= sZ; ++t){
      float S = waveSum(v);
      const float* rp = ring[cur];
      float s0=0.f,s1=0.f,s2=0.f,s3=0.f;
#pragma unroll
      for (int i = 0; i < Hn; i += 4){
        float4 a = *(const float4*)(rp + i);
        s0 = fmaf(a.x, pt[i+0], s0); s1 = fmaf(a.y, pt[i+1], s1);
        s2 = fmaf(a.z, pt[i+2], s2); s3 = fmaf(a.w, pt[i+3], s3);
      }
      float sd = (s0+s1)+(s2+s3);
      float e = act ? ldsE[(t - row_lo)*Hn + lane] : 0.f;
      float vn = act ? e * sd * (1.f/S) : 0.f;
      cur ^= 1;
      if (act) ring[cur][lane] = vn;
      __syncthreads();
      if (act && t >= t0) ws[laF + (size_t)t*Hn + lane] = vn;
      v = vn;
    }
  } else {
    const size_t lbF = OFF_LB + (size_t)b * Tn * Hn;
    float v = act ? 1.f : 0.f;
    if (exact && c == (Tn/FBL - 1) && act) ws[lbF + (size_t)(Tn-1)*Hn + lane] = 1.f;
    int cur = 0;
    for (int t = sA; t >= sZ; --t){
      float e = act ? ldsE[(t - row_lo)*Hn + lane] : 0.f;
      float wv = e * v;
      if (act) ring[cur][lane] = wv;
      float S = waveSum(wv);
      __syncthreads();
      const float* rp = ring[cur];
      float s0=0.f,s1=0.f,s2=0.f,s3=0.f;
#pragma unroll
      for (int j = 0; j < Hn; j += 4){
        float4 a = *(const float4*)(rp + j);
        s0 = fmaf(a.x, pt[j+0], s0); s1 = fmaf(a.y, pt[j+1], s1);
        s2 = fmaf(a.z, pt[j+2], s2); s3 = fmaf(a.w, pt[j+3], s3);
      }
      float vn = act ? ((s0+s1)+(s2+s3)) * (1.f/S) : 0.f;
      cur ^= 1;
      if (act && t <= te) ws[lbF + (size_t)t*Hn + lane] = vn;
      v = vn;
    }
  }
}

// -------- gamma / xi / masked accumulation (prob domain, no atomics) -----------
// One coalesced partial store per block; sum_kernel reduces. (R9's last-block
// counter pattern = 8192 serialized same-address atomics+fences = 165us. Never
// funnel per-block completion through one address on this chip.)
__global__ __launch_bounds__(256) void gamma_xi_kernel(
    const float* __restrict__ ws_c, float* __restrict__ ws,
    const int* __restrict__ seq_len){
  __shared__ float y_s[Hn], lap_s[Hn];
  __shared__ float red[8];
  const int tid = threadIdx.x;
  const int bid = blockIdx.x;
  const int b = bid >> 9, t = bid & (Tn-1);
  const int len = seq_len[b];
  int tb = t + (Tn - len); if (tb >= Tn) tb -= Tn;
  const size_t bt = (size_t)b*Tn + t;
  float lep = 0.f;
  if (tid < Hn){
    const float* lpp = ws_c + OFF_LEPP + bt*Gn + tid;
    lep = lpp[0] + lpp[Hn] + lpp[2*Hn] + lpp[3*Hn];
    float lb  = ws_c[OFF_LB + ((size_t)b*Tn + tb)*Hn + tid];
    y_s[tid] = __expf(lep) * lb;
    if (t >= 1) lap_s[tid] = ws_c[OFF_LA + (bt-1)*Hn + tid];
  }
  float emis_term = 0.f, prior_term = 0.f;
  if (tid < 64){
    int h = (tid < Hn) ? tid : 0;
    float la  = ws_c[OFF_LA + bt*Hn + h];
    float lb  = ws_c[OFF_LB + ((size_t)b*Tn + tb)*Hn + h];
    float lp  = ws_c[OFF_LP + h];
    float wgt = (tid < Hn) ? la*lb : 0.f;
    float Z = waveSum(wgt);
    float inv = 1.f / Z;
    emis_term  = waveSum(wgt * lep) * inv;
    prior_term = waveSum(wgt * lp) * inv;
  }
  __syncthreads();
  float tran_term = 0.f;
  if (t >= 1){
    float se = 0.f, st = 0.f;
#pragma unroll
    for (int k=0;k<9;++k){
      int e = tid + k*256;
      int i = e / Hn, j = e - i*Hn;
      float e2 = ws_c[OFF_PT + e] * lap_s[i] * y_s[j];
      se += e2;
      st = fmaf(e2, ws_c[OFF_LT + e], st);
    }
    se = waveSum(se);
    st = waveSum(st);
    const int wid = tid >> 6;
    if ((tid & 63) == 0){ red[wid] = se; red[4+wid] = st; }
    __syncthreads();
    if (tid == 0){
      float SE = red[0]+red[1]+red[2]+red[3];
      float ST = red[4]+red[5]+red[6]+red[7];
      tran_term = ST / SE;
    }
  }
  if (tid == 0){
    float tot = 0.f;
    if (t < len)            tot += emis_term;
    if (t == 0)             tot += prior_term;
    if (t >= 1 && t < len)  tot += tran_term;
    ws[OFF_RED + bid] = tot;
  }
}

// ---------------- final reduction: 8192 partials -> scalar ---------------------
__global__ __launch_bounds__(256) void sum_kernel(const float* __restrict__ ws,
                                                  float* __restrict__ out){
  __shared__ float red[4];
  const int tid = threadIdx.x;
  float s = 0.f;
  for (int i = tid; i < Mn; i += 256) s += ws[OFF_RED + i];
  s = waveSum(s);
  if ((tid & 63) == 0) red[tid >> 6] = s;
  __syncthreads();
  if (tid == 0) out[0] = (red[0]+red[1]+red[2]+red[3]) * (1.f / Bn);
}

} // namespace

extern "C" void kernel_launch(void* const* d_in, const int* in_sizes, int n_in,
                              void* d_out, int out_size, void* d_ws, size_t ws_size,
                              hipStream_t stream){
  const float* emb = (const float*)d_in[0];
  const float* obs = (const float*)d_in[1];
  const float* sp  = (const float*)d_in[2];
  const float* ut  = (const float*)d_in[3];
  const float* ue  = (const float*)d_in[4];
  const float* Wm  = (const float*)d_in[5];
  const float* bm  = (const float*)d_in[6];
  const int*   sl  = (const int*)d_in[7];
  float* ws  = (float*)d_ws;
  float* out = (float*)d_out;
  (void)in_sizes; (void)n_in; (void)ws_size; (void)out_size;

  unsigned short* embB = (unsigned short*)(ws + FLOATS_END);
  unsigned short* WB   = embB + (size_t)Mn * Dn;

  const int n4a = Mn*Dn/4, n4b = Nn*Dn/4;
  const int nconv = (n4a + n4b + 255)/256;
  convprep_kernel<<<nconv + 1, 256, 0, stream>>>(emb, embB, n4a, Wm, WB, n4b,
                                                 sp, ut, ue, ws, nconv);
  gemm_lep_kernel<<<dim3(Mn/MT, Nn/NT2), 256, 0, stream>>>(embB, WB, bm, obs, ws);
  fb_kernel<<<dim3(Tn/FBL, Bn, 2), 64, 0, stream>>>(ws);
  gamma_xi_kernel<<<Bn*Tn, 256, 0, stream>>>(ws, ws, sl);
  sum_kernel<<<1, 256, 0, stream>>>(ws, out);
}